// Round 5
// baseline (390.557 us; speedup 1.0000x reference)
//
#include <hip/hip_runtime.h>
#include <hip/hip_bf16.h>
#include <stdint.h>
#include <stddef.h>

typedef __bf16 bf16_t;
typedef __bf16 bf16x4_t __attribute__((ext_vector_type(4)));
typedef __bf16 bf16x8_t __attribute__((ext_vector_type(8)));
typedef float f32x4 __attribute__((ext_vector_type(4)));

#define D_MODEL 2048
#define NHEADS 16
#define HDIM 128
#define SEQ 2048
#define BATCH 2
#define MTOT (BATCH * SEQ) /* 4096 */
#define SCALE_F 0.08838834764831845f /* 1/sqrt(128) */
#define LOG2E 1.4426950408889634f
#define QSCALE (SCALE_F * LOG2E)
#define KT 64            /* flash K-tile */
#define NEGI -3.0e38f    /* mask value */
#define MINIT -1.0e30f   /* finite m sentinel: keeps exp2(masked - m) == 0 */
#define DEFER_THR 8.0f   /* T13 defer-max threshold (log2 units) */

#define AS1 __attribute__((address_space(1)))
#define AS3 __attribute__((address_space(3)))

__device__ __forceinline__ void load_lds16(const bf16_t* g, bf16_t* l) {
  __builtin_amdgcn_global_load_lds((AS1 void*)(g), (AS3 void*)(l), 16, 0, 0);
}

// ---------------------------------------------------------------- casts fp32->bf16
__global__ void cast_kernel(const float* __restrict__ src, bf16_t* __restrict__ dst, int n4) {
  int i = blockIdx.x * blockDim.x + threadIdx.x;
  if (i < n4) {
    float4 v = ((const float4*)src)[i];
    bf16x4_t o;
    o.x = (bf16_t)v.x; o.y = (bf16_t)v.y; o.z = (bf16_t)v.z; o.w = (bf16_t)v.w;
    ((bf16x4_t*)dst)[i] = o;
  }
}

__global__ void cast4_kernel(const float* __restrict__ s0, const float* __restrict__ s1,
                             const float* __restrict__ s2, const float* __restrict__ s3,
                             bf16_t* __restrict__ dst, int n4) {
  int i = blockIdx.x * blockDim.x + threadIdx.x;
  int y = blockIdx.y;
  if (i < n4) {
    const float* src = (y == 0) ? s0 : (y == 1) ? s1 : (y == 2) ? s2 : s3;
    float4 v = ((const float4*)src)[i];
    bf16x4_t o;
    o.x = (bf16_t)v.x; o.y = (bf16_t)v.y; o.z = (bf16_t)v.z; o.w = (bf16_t)v.w;
    ((bf16x4_t*)(dst + (size_t)y * D_MODEL * D_MODEL / 4 * 4))[i] = o;
  }
}

// ---------------------------------------------------------------- GEMM  C = A @ B^T (+bias)
// BK=64, XOR chunk-swizzled LDS. mode 0: N=6144 (q|k|v) -> Q (prescaled by QSCALE), K,
// V transposed. mode 1: N=2048 -> fp32 out + bias.
// (Proven: ~122 us / 855 TF on the QKV shape = 95% of the m97-structure ceiling. 256^2
// 8-phase refuted for this shape: 384 tiles @ 1 blk/CU = 1.5 rounds packing; rounds 1-2.)
__global__ __launch_bounds__(256) void gemm_fused(
    const bf16_t* __restrict__ A, const bf16_t* __restrict__ Bm, int mode,
    const float* __restrict__ bias0, const float* __restrict__ bias1,
    const float* __restrict__ bias2,
    bf16_t* __restrict__ Qo, bf16_t* __restrict__ Ko, bf16_t* __restrict__ Vto,
    float* __restrict__ Out) {
  const int K = 2048;
  __shared__ __align__(16) bf16_t lA[128 * 64];
  __shared__ __align__(16) bf16_t lB[128 * 64];
  const int m0 = blockIdx.x * 128;
  const int n0 = blockIdx.y * 128;
  const int t = threadIdx.x;
  const int w = t >> 6, lane = t & 63;
  const int wm = w & 1, wn = w >> 1;
  const int la = lane & 15, lb = lane >> 4;

  f32x4 acc[4][4];
  f32x4 zero = {0.f, 0.f, 0.f, 0.f};
#pragma unroll
  for (int i = 0; i < 4; i++)
#pragma unroll
    for (int j = 0; j < 4; j++) acc[i][j] = zero;

  const int row0 = t >> 3, cc = t & 7;
  const int ccs = cc ^ (row0 & 7);
  const bf16_t* gA = A + (size_t)(m0 + row0) * K + ccs * 8;
  const bf16_t* gB = Bm + (size_t)(n0 + row0) * K + ccs * 8;
  bf16_t* sA = lA + t * 8;
  bf16_t* sB = lB + t * 8;

  for (int k0 = 0; k0 < K; k0 += 64) {
    __syncthreads();
#pragma unroll
    for (int i = 0; i < 4; i++)
      load_lds16(gA + k0 + (size_t)(32 * i) * K, sA + 2048 * i);
#pragma unroll
    for (int i = 0; i < 4; i++)
      load_lds16(gB + k0 + (size_t)(32 * i) * K, sB + 2048 * i);
    __syncthreads();
#pragma unroll
    for (int ks = 0; ks < 2; ks++) {
      bf16x8_t af[4], bfr[4];
#pragma unroll
      for (int mt = 0; mt < 4; mt++) {
        int row = wm * 64 + mt * 16 + la;
        af[mt] = *(const bf16x8_t*)(lA + row * 64 + (((ks * 4 + lb) ^ (la & 7)) * 8));
      }
#pragma unroll
      for (int nt = 0; nt < 4; nt++) {
        int row = wn * 64 + nt * 16 + la;
        bfr[nt] = *(const bf16x8_t*)(lB + row * 64 + (((ks * 4 + lb) ^ (la & 7)) * 8));
      }
#pragma unroll
      for (int mt = 0; mt < 4; mt++)
#pragma unroll
        for (int nt = 0; nt < 4; nt++)
          acc[mt][nt] = __builtin_amdgcn_mfma_f32_16x16x32_bf16(af[mt], bfr[nt], acc[mt][nt], 0, 0, 0);
    }
  }

  if (mode == 0) {
#pragma unroll
    for (int mt = 0; mt < 4; mt++) {
#pragma unroll
      for (int nt = 0; nt < 4; nt++) {
        int m = m0 + wm * 64 + mt * 16 + lb * 4;
        int n = n0 + wn * 64 + nt * 16 + la;
        int b = m >> 11, s = m & 2047;
        int which = n >> 11, hd = n & 2047;
        int h = hd >> 7, d = hd & 127;
        float bv = (which == 0 ? bias0 : which == 1 ? bias1 : bias2)[hd];
        f32x4 v = acc[mt][nt];
        if (which == 2) {
          bf16_t* dst = Vto + ((size_t)(b * NHEADS + h) * HDIM + d) * SEQ + s;
          bf16x4_t pk;
          pk.x = (bf16_t)(v.x + bv); pk.y = (bf16_t)(v.y + bv);
          pk.z = (bf16_t)(v.z + bv); pk.w = (bf16_t)(v.w + bv);
          *(bf16x4_t*)dst = pk;
        } else {
          float sc = (which == 0) ? QSCALE : 1.0f;
          bf16_t* dst = (which == 0 ? Qo : Ko) + ((size_t)(b * NHEADS + h) * SEQ + s) * HDIM + d;
          dst[0]        = (bf16_t)((v.x + bv) * sc);
          dst[HDIM]     = (bf16_t)((v.y + bv) * sc);
          dst[2 * HDIM] = (bf16_t)((v.z + bv) * sc);
          dst[3 * HDIM] = (bf16_t)((v.w + bv) * sc);
        }
      }
    }
  } else {
#pragma unroll
    for (int mt = 0; mt < 4; mt++) {
#pragma unroll
      for (int nt = 0; nt < 4; nt++) {
        int m = m0 + wm * 64 + mt * 16 + lb * 4;
        int n = n0 + wn * 64 + nt * 16 + la;
        float bv = bias0[n];
        f32x4 v = acc[mt][nt];
        float* dst = Out + (size_t)m * D_MODEL + n;
        dst[0]           = v.x + bv;
        dst[D_MODEL]     = v.y + bv;
        dst[2 * D_MODEL] = v.z + bv;
        dst[3 * D_MODEL] = v.w + bv;
      }
    }
  }
}

// ---------------------------------------------------------------- causal flash attention
// 8-WARP blocks (512 thr), q-tile 256, KT=64, K AND V double-buffered (LDS 100KB, exactly
// 1 block/CU, grid 256 = 1/CU). With both operands dbuf the MID barrier is unnecessary:
// step-top __syncthreads guarantees (a) all warps finished previous step's reads before
// anyone overwrites buf^1, (b) per-wave vmcnt(0) drain covers loads issued a FULL step
// earlier (= free). -> ONE barrier per step, 18 steps/block (vs 2x34 barrier-events of
// the round-3 version). Same wave count per CU (8), so latency hiding unchanged.
// Uniform decomposition: 144 total steps per bh over 8 blocks = 18 each.
//   idx<4:  qt=4+idx, partial [0,18), slot (idx*32+bh)*2.
//   idx>=4: qtA=idx-4 full [0,4qtA+4), then qt'=7-qtA partial [18, 32-4qtA),
//           slot ((3-qtA)*32+bh)*2+1.  (4qtA+4) + (14-4qtA) = 18 steps.
// T13 defer-max: skip alpha-rescale when __all(tm - m <= 8).
__global__ __launch_bounds__(512, 2) void flash_attn(
    const bf16_t* __restrict__ Q, const bf16_t* __restrict__ Kg,
    const bf16_t* __restrict__ Vt, bf16_t* __restrict__ O,
    bf16_t* __restrict__ PO, float* __restrict__ ML) {
  __shared__ __align__(16) bf16_t lK[2][KT * 128];   // [j][d] chunks, swizzled; 2x16KB
  __shared__ __align__(16) bf16_t lV[2][128 * KT];   // [d][j] chunks, swizzled; 2x16KB
  __shared__ __align__(16) bf16_t lP[256 * 72];      // P^T as [q][j], stride 72; 36KB
  const int g = blockIdx.x;
  const int bh = g & 31, idx = g >> 5;   // idx in [0,8)
  const int t = threadIdx.x;
  const int w = t >> 6, lane = t & 63;   // 8 warps
  const int la = lane & 15, lb = lane >> 4;
  const int qloc = w * 32 + la;          // warp w owns q-rows w*32 + {0..15, 16..31}

  const bf16_t* Qb = Q + (size_t)bh * SEQ * HDIM;
  const bf16_t* Kb = Kg + (size_t)bh * SEQ * HDIM;
  const bf16_t* Vb = Vt + (size_t)bh * HDIM * SEQ;
  const int b = bh >> 4, h = bh & 15;

  int nph, qts[2], k0s[2], k1s[2], slots[2];
  bool parts[2];
  if (idx < 4) {
    nph = 1; qts[0] = 4 + idx; k0s[0] = 0; k1s[0] = 18;
    parts[0] = true; slots[0] = (idx * 32 + bh) * 2;
  } else {
    int qtA = idx - 4;
    nph = 2;
    qts[0] = qtA; k0s[0] = 0; k1s[0] = 4 * qtA + 4; parts[0] = false; slots[0] = 0;
    qts[1] = 7 - qtA; k0s[1] = 18; k1s[1] = 32 - 4 * qtA;
    parts[1] = true; slots[1] = ((3 - qtA) * 32 + bh) * 2 + 1;
  }

  // staging lane roles (fixed per thread); XOR chunk swizzles are involutions.
  const int krow = t >> 4, kcc = t & 15;   // K: 2 iters cover 64 rows x 16 chunks
  const int kccx = kcc ^ (krow & 15);      // (row&15) invariant under +32i
  const int vrow = t >> 3, vjc = t & 7;    // V: 2 iters cover 128 rows x 8 chunks
  const int vccx = vjc ^ (vrow & 7);       // (row&7) invariant under +64i

  auto stageKV = [&](int buf, int j0) {
#pragma unroll
    for (int i = 0; i < 2; i++)
      load_lds16(Kb + (size_t)(j0 + krow + 32 * i) * HDIM + kccx * 8,
                 lK[buf] + (t + 512 * i) * 8);
#pragma unroll
    for (int i = 0; i < 2; i++)
      load_lds16(Vb + (size_t)(vrow + 64 * i) * SEQ + j0 + vccx * 8,
                 lV[buf] + (t + 512 * i) * 8);
  };

  for (int ph = 0; ph < nph; ph++) {
    const int qt = qts[ph], kt0 = k0s[ph], kt1 = k1s[ph];
    const int q0 = qt * 256;

    // Q fragments (B-operand): Q[q0+qloc+16mt][32ks+8lb+i], prescaled by QSCALE
    bf16x8_t qf[2][4];
#pragma unroll
    for (int mt = 0; mt < 2; mt++)
#pragma unroll
      for (int ks = 0; ks < 4; ks++)
        qf[mt][ks] = *(const bf16x8_t*)(Qb + (size_t)(q0 + qloc + mt * 16) * HDIM + ks * 32 + lb * 8);

    f32x4 oacc[2][8];
    float mr[2] = {MINIT, MINIT}, lr[2] = {0.f, 0.f};
    f32x4 zero = {0.f, 0.f, 0.f, 0.f};
#pragma unroll
    for (int mt = 0; mt < 2; mt++)
#pragma unroll
      for (int dt = 0; dt < 8; dt++) oacc[mt][dt] = zero;

    // phase prologue: barrier protects lK/lV still read by the previous phase's tail.
    __syncthreads();
    stageKV(kt0 & 1, kt0 * KT);

    for (int kt = kt0; kt < kt1; kt++) {
      const int j0 = kt * KT;
      const int cur = kt & 1;

      // ONE barrier per step: per-wave vmcnt(0)+lgkm(0) drain (loads issued a full step
      // ago -> cheap) + s_barrier. After it, buf cur is fully resident for ALL warps,
      // and buf cur^1 is provably dead (everyone finished step kt-1) -> safe to restage.
      __syncthreads();
      if (kt + 1 < kt1) stageKV(cur ^ 1, (kt + 1) * KT);

      // S^T = K Q^T : rows j (4 nt tiles of 16), cols q (2 mt tiles)
      f32x4 st[4][2];
#pragma unroll
      for (int nt = 0; nt < 4; nt++)
#pragma unroll
        for (int mt = 0; mt < 2; mt++) st[nt][mt] = zero;
#pragma unroll
      for (int ks = 0; ks < 4; ks++) {
#pragma unroll
        for (int nt = 0; nt < 4; nt++) {
          int j = nt * 16 + la;
          int ck = (ks * 4 + lb) ^ la;   // j&15 == la
          bf16x8_t kf = *(const bf16x8_t*)(lK[cur] + j * 128 + ck * 8);
#pragma unroll
          for (int mt = 0; mt < 2; mt++)
            st[nt][mt] = __builtin_amdgcn_mfma_f32_16x16x32_bf16(kf, qf[mt][ks], st[nt][mt], 0, 0, 0);
        }
      }

      const bool dm = (j0 + KT > q0);  // diagonal-straddling (block-uniform)
#pragma unroll
      for (int mt = 0; mt < 2; mt++) {
        int qg = q0 + qloc + mt * 16;
        if (dm) {
#pragma unroll
          for (int nt = 0; nt < 4; nt++)
#pragma unroll
            for (int r = 0; r < 4; r++)
              if (j0 + nt * 16 + lb * 4 + r > qg) st[nt][mt][r] = NEGI;
        }
        float tm = NEGI;
#pragma unroll
        for (int nt = 0; nt < 4; nt++)
#pragma unroll
          for (int r = 0; r < 4; r++) tm = fmaxf(tm, st[nt][mt][r]);
        tm = fmaxf(tm, __shfl_xor(tm, 16));
        tm = fmaxf(tm, __shfl_xor(tm, 32));
        // T13 defer-max: only rescale when some row's max grew by > THR.
        if (!__all(tm - mr[mt] <= DEFER_THR)) {
          float mnew = fmaxf(mr[mt], tm);
          float alpha = exp2f(mr[mt] - mnew);
          lr[mt] *= alpha;
#pragma unroll
          for (int dt = 0; dt < 8; dt++) oacc[mt][dt] *= alpha;
          mr[mt] = mnew;
        }
        float s = 0.f;
#pragma unroll
        for (int nt = 0; nt < 4; nt++) {
          f32x4 p;
#pragma unroll
          for (int r = 0; r < 4; r++) {
            p[r] = exp2f(st[nt][mt][r] - mr[mt]);
            s += p[r];
          }
          bf16x4_t pk;
          pk.x = (bf16_t)p[0]; pk.y = (bf16_t)p[1]; pk.z = (bf16_t)p[2]; pk.w = (bf16_t)p[3];
          *(bf16x4_t*)(lP + (qloc + mt * 16) * 72 + nt * 16 + lb * 4) = pk;
        }
        s += __shfl_xor(s, 16);
        s += __shfl_xor(s, 32);
        lr[mt] += s;
      }

      // O^T += V^T P^T  (j = 64 -> two ks slices). lP rows are warp-local: the
      // compiler's lgkm waits order same-warp write->read; no barrier needed.
      bf16x8_t pf[2][2];
#pragma unroll
      for (int mt = 0; mt < 2; mt++)
#pragma unroll
        for (int ksv = 0; ksv < 2; ksv++)
          pf[mt][ksv] = *(const bf16x8_t*)(lP + (qloc + mt * 16) * 72 + ksv * 32 + lb * 8);
#pragma unroll
      for (int dt = 0; dt < 8; dt++) {
        int d = dt * 16 + la;
#pragma unroll
        for (int ksv = 0; ksv < 2; ksv++) {
          int jc = (ksv * 4 + lb) ^ (d & 7);
          bf16x8_t vf = *(const bf16x8_t*)(lV[cur] + d * 64 + jc * 8);
#pragma unroll
          for (int mt = 0; mt < 2; mt++)
            oacc[mt][dt] = __builtin_amdgcn_mfma_f32_16x16x32_bf16(vf, pf[mt][ksv], oacc[mt][dt], 0, 0, 0);
        }
      }
    }

    if (!parts[ph]) {
#pragma unroll
      for (int mt = 0; mt < 2; mt++) {
        float inv = 1.0f / lr[mt];
        int q = q0 + qloc + mt * 16;
        bf16_t* dst = O + ((size_t)b * SEQ + q) * D_MODEL + h * HDIM + lb * 4;
#pragma unroll
        for (int dt = 0; dt < 8; dt++) {
          f32x4 v = oacc[mt][dt];
          bf16x4_t pk;
          pk.x = (bf16_t)(v[0] * inv); pk.y = (bf16_t)(v[1] * inv);
          pk.z = (bf16_t)(v[2] * inv); pk.w = (bf16_t)(v[3] * inv);
          *(bf16x4_t*)(dst + dt * 16) = pk;
        }
      }
    } else {
      const int slot = slots[ph];
      bf16_t* pob = PO + (size_t)slot * 256 * 128;
#pragma unroll
      for (int mt = 0; mt < 2; mt++) {
        int q = qloc + mt * 16;
        bf16_t* dst = pob + (size_t)q * 128 + lb * 4;
#pragma unroll
        for (int dt = 0; dt < 8; dt++) {
          f32x4 v = oacc[mt][dt];
          bf16x4_t pk;
          pk.x = (bf16_t)v[0]; pk.y = (bf16_t)v[1];
          pk.z = (bf16_t)v[2]; pk.w = (bf16_t)v[3];
          *(bf16x4_t*)(dst + dt * 16) = pk;
        }
        if (lb == 0) {
          float2 ml = make_float2(mr[mt], lr[mt]);
          *(float2*)(ML + ((size_t)slot * 256 + q) * 2) = ml;
        }
      }
    }
  }
}

// ---------------------------------------------------------------- merge split-j partials
// 4 split q-tiles (qt=4..7) x 32 bh, 256 rows each. 128 blocks x 512 threads.
__global__ void merge_kernel(const bf16_t* __restrict__ PO, const float* __restrict__ ML,
                             bf16_t* __restrict__ O) {
  const int qti = blockIdx.x >> 5, bh = blockIdx.x & 31;
  const int qt = 4 + qti;
  const int t = threadIdx.x;
  const int q = t >> 1, dh = (t & 1) * 64;
  const size_t s1 = ((size_t)(qti * 32 + bh)) * 2;
  const float* ml1 = ML + (s1 * 256 + q) * 2;
  const float* ml2 = ML + ((s1 + 1) * 256 + q) * 2;
  float m1 = ml1[0], l1 = ml1[1], m2 = ml2[0], l2 = ml2[1];
  float m = fmaxf(m1, m2);
  float w1 = exp2f(m1 - m), w2 = exp2f(m2 - m);
  float inv = 1.0f / (w1 * l1 + w2 * l2);
  w1 *= inv; w2 *= inv;
  const bf16_t* p1 = PO + (s1 * 256 + q) * 128 + dh;
  const bf16_t* p2 = PO + ((s1 + 1) * 256 + q) * 128 + dh;
  const int b = bh >> 4, h = bh & 15;
  bf16_t* dst = O + ((size_t)b * SEQ + qt * 256 + q) * D_MODEL + h * HDIM + dh;
#pragma unroll
  for (int i = 0; i < 8; i++) {
    bf16x8_t a = ((const bf16x8_t*)p1)[i];
    bf16x8_t c = ((const bf16x8_t*)p2)[i];
    bf16x8_t o;
#pragma unroll
    for (int e = 0; e < 8; e++)
      o[e] = (bf16_t)(w1 * (float)a[e] + w2 * (float)c[e]);
    ((bf16x8_t*)dst)[i] = o;
  }
}

// ---------------------------------------------------------------- launch
extern "C" void kernel_launch(void* const* d_in, const int* in_sizes, int n_in,
                              void* d_out, int out_size, void* d_ws, size_t ws_size,
                              hipStream_t stream) {
  (void)in_sizes; (void)n_in; (void)out_size; (void)ws_size;
  const float* x  = (const float*)d_in[0];
  const float* Wq = (const float*)d_in[2];
  const float* bq = (const float*)d_in[3];
  const float* Wk = (const float*)d_in[4];
  const float* bk = (const float*)d_in[5];
  const float* Wv = (const float*)d_in[6];
  const float* bv = (const float*)d_in[7];
  const float* Wo = (const float*)d_in[8];
  const float* bo = (const float*)d_in[9];
  float* out = (float*)d_out;

  const size_t NBF = (size_t)MTOT * D_MODEL * sizeof(bf16_t);    // 16.8 MB
  const size_t WBF = (size_t)D_MODEL * D_MODEL * sizeof(bf16_t); // 8.4 MB
  char* p = (char*)d_ws;
  bf16_t* xb   = (bf16_t*)p; p += NBF;       // reused as attention output O
  bf16_t* Wcat = (bf16_t*)p; p += 4 * WBF;   // [Wq|Wk|Wv|Wo] bf16
  bf16_t* Qb   = (bf16_t*)p; p += NBF;
  bf16_t* Kb   = (bf16_t*)p; p += NBF;
  bf16_t* Vtb  = (bf16_t*)p; p += NBF;
  bf16_t* Wob  = Wcat + (size_t)3 * D_MODEL * D_MODEL;
  bf16_t* Ob   = xb;
  // Partial buffers overlay dead Wq|Wk|Wv bf16 slots (dead after QKV GEMM):
  bf16_t* PO = Wcat;                                     // 256 slots * 256*128 bf16 = 16.8 MB
  float*  ML = (float*)(Wcat + (size_t)256 * 256 * 128); // 0.5 MB

  const int WN4 = D_MODEL * D_MODEL / 4;
  const int XN4 = MTOT * D_MODEL / 4;
  cast_kernel<<<XN4 / 256, 256, 0, stream>>>(x, xb, XN4);
  cast4_kernel<<<dim3(WN4 / 256, 4), 256, 0, stream>>>(Wq, Wk, Wv, Wo, Wcat, WN4);

  gemm_fused<<<dim3(MTOT / 128, 6144 / 128), 256, 0, stream>>>(
      xb, Wcat, 0, bq, bk, bv, Qb, Kb, Vtb, nullptr);

  flash_attn<<<dim3(256), 512, 0, stream>>>(Qb, Kb, Vtb, Ob, PO, ML);
  merge_kernel<<<dim3(128), 512, 0, stream>>>(PO, ML, Ob);

  gemm_fused<<<dim3(MTOT / 128, D_MODEL / 128), 256, 0, stream>>>(
      Ob, Wob, 1, bo, nullptr, nullptr, nullptr, nullptr, nullptr, out);
}

// Round 6
// 383.287 us; speedup vs baseline: 1.0190x; 1.0190x over previous
//
#include <hip/hip_runtime.h>
#include <hip/hip_bf16.h>
#include <stdint.h>
#include <stddef.h>

typedef __bf16 bf16_t;
typedef __bf16 bf16x4_t __attribute__((ext_vector_type(4)));
typedef __bf16 bf16x8_t __attribute__((ext_vector_type(8)));
typedef float f32x4 __attribute__((ext_vector_type(4)));

#define D_MODEL 2048
#define NHEADS 16
#define HDIM 128
#define SEQ 2048
#define BATCH 2
#define MTOT (BATCH * SEQ) /* 4096 */
#define SCALE_F 0.08838834764831845f /* 1/sqrt(128) */
#define LOG2E 1.4426950408889634f
#define QSCALE (SCALE_F * LOG2E)
#define KT 64            /* flash K-tile */
#define NEGI -3.0e38f    /* mask value */
#define MINIT -1.0e30f   /* finite m sentinel: keeps exp2(masked - m) == 0 */
#define DEFER_THR 8.0f   /* T13 defer-max threshold (log2 units) */

#define AS1 __attribute__((address_space(1)))
#define AS3 __attribute__((address_space(3)))

__device__ __forceinline__ void load_lds16(const bf16_t* g, bf16_t* l) {
  __builtin_amdgcn_global_load_lds((AS1 void*)(g), (AS3 void*)(l), 16, 0, 0);
}

// ---------------------------------------------------------------- casts fp32->bf16
__global__ void cast_kernel(const float* __restrict__ src, bf16_t* __restrict__ dst, int n4) {
  int i = blockIdx.x * blockDim.x + threadIdx.x;
  if (i < n4) {
    float4 v = ((const float4*)src)[i];
    bf16x4_t o;
    o.x = (bf16_t)v.x; o.y = (bf16_t)v.y; o.z = (bf16_t)v.z; o.w = (bf16_t)v.w;
    ((bf16x4_t*)dst)[i] = o;
  }
}

__global__ void cast4_kernel(const float* __restrict__ s0, const float* __restrict__ s1,
                             const float* __restrict__ s2, const float* __restrict__ s3,
                             bf16_t* __restrict__ dst, int n4) {
  int i = blockIdx.x * blockDim.x + threadIdx.x;
  int y = blockIdx.y;
  if (i < n4) {
    const float* src = (y == 0) ? s0 : (y == 1) ? s1 : (y == 2) ? s2 : s3;
    float4 v = ((const float4*)src)[i];
    bf16x4_t o;
    o.x = (bf16_t)v.x; o.y = (bf16_t)v.y; o.z = (bf16_t)v.z; o.w = (bf16_t)v.w;
    ((bf16x4_t*)(dst + (size_t)y * D_MODEL * D_MODEL / 4 * 4))[i] = o;
  }
}

// ---------------------------------------------------------------- GEMM  C = A @ B^T (+bias)
// BK=64, XOR chunk-swizzled LDS. mode 0: N=6144 (q|k|v) -> Q (prescaled by QSCALE), K,
// V transposed. mode 1: N=2048 -> fp32 out + bias.
// (Proven: ~122 us / 855 TF on the QKV shape = 95% of the m97-structure ceiling. 256^2
// 8-phase refuted for this shape: 384 tiles @ 1 blk/CU = 1.5 rounds packing; rounds 1-2.)
__global__ __launch_bounds__(256) void gemm_fused(
    const bf16_t* __restrict__ A, const bf16_t* __restrict__ Bm, int mode,
    const float* __restrict__ bias0, const float* __restrict__ bias1,
    const float* __restrict__ bias2,
    bf16_t* __restrict__ Qo, bf16_t* __restrict__ Ko, bf16_t* __restrict__ Vto,
    float* __restrict__ Out) {
  const int K = 2048;
  __shared__ __align__(16) bf16_t lA[128 * 64];
  __shared__ __align__(16) bf16_t lB[128 * 64];
  const int m0 = blockIdx.x * 128;
  const int n0 = blockIdx.y * 128;
  const int t = threadIdx.x;
  const int w = t >> 6, lane = t & 63;
  const int wm = w & 1, wn = w >> 1;
  const int la = lane & 15, lb = lane >> 4;

  f32x4 acc[4][4];
  f32x4 zero = {0.f, 0.f, 0.f, 0.f};
#pragma unroll
  for (int i = 0; i < 4; i++)
#pragma unroll
    for (int j = 0; j < 4; j++) acc[i][j] = zero;

  const int row0 = t >> 3, cc = t & 7;
  const int ccs = cc ^ (row0 & 7);
  const bf16_t* gA = A + (size_t)(m0 + row0) * K + ccs * 8;
  const bf16_t* gB = Bm + (size_t)(n0 + row0) * K + ccs * 8;
  bf16_t* sA = lA + t * 8;
  bf16_t* sB = lB + t * 8;

  for (int k0 = 0; k0 < K; k0 += 64) {
    __syncthreads();
#pragma unroll
    for (int i = 0; i < 4; i++)
      load_lds16(gA + k0 + (size_t)(32 * i) * K, sA + 2048 * i);
#pragma unroll
    for (int i = 0; i < 4; i++)
      load_lds16(gB + k0 + (size_t)(32 * i) * K, sB + 2048 * i);
    __syncthreads();
#pragma unroll
    for (int ks = 0; ks < 2; ks++) {
      bf16x8_t af[4], bfr[4];
#pragma unroll
      for (int mt = 0; mt < 4; mt++) {
        int row = wm * 64 + mt * 16 + la;
        af[mt] = *(const bf16x8_t*)(lA + row * 64 + (((ks * 4 + lb) ^ (la & 7)) * 8));
      }
#pragma unroll
      for (int nt = 0; nt < 4; nt++) {
        int row = wn * 64 + nt * 16 + la;
        bfr[nt] = *(const bf16x8_t*)(lB + row * 64 + (((ks * 4 + lb) ^ (la & 7)) * 8));
      }
#pragma unroll
      for (int mt = 0; mt < 4; mt++)
#pragma unroll
        for (int nt = 0; nt < 4; nt++)
          acc[mt][nt] = __builtin_amdgcn_mfma_f32_16x16x32_bf16(af[mt], bfr[nt], acc[mt][nt], 0, 0, 0);
    }
  }

  if (mode == 0) {
#pragma unroll
    for (int mt = 0; mt < 4; mt++) {
#pragma unroll
      for (int nt = 0; nt < 4; nt++) {
        int m = m0 + wm * 64 + mt * 16 + lb * 4;
        int n = n0 + wn * 64 + nt * 16 + la;
        int b = m >> 11, s = m & 2047;
        int which = n >> 11, hd = n & 2047;
        int h = hd >> 7, d = hd & 127;
        float bv = (which == 0 ? bias0 : which == 1 ? bias1 : bias2)[hd];
        f32x4 v = acc[mt][nt];
        if (which == 2) {
          bf16_t* dst = Vto + ((size_t)(b * NHEADS + h) * HDIM + d) * SEQ + s;
          bf16x4_t pk;
          pk.x = (bf16_t)(v.x + bv); pk.y = (bf16_t)(v.y + bv);
          pk.z = (bf16_t)(v.z + bv); pk.w = (bf16_t)(v.w + bv);
          *(bf16x4_t*)dst = pk;
        } else {
          float sc = (which == 0) ? QSCALE : 1.0f;
          bf16_t* dst = (which == 0 ? Qo : Ko) + ((size_t)(b * NHEADS + h) * SEQ + s) * HDIM + d;
          dst[0]        = (bf16_t)((v.x + bv) * sc);
          dst[HDIM]     = (bf16_t)((v.y + bv) * sc);
          dst[2 * HDIM] = (bf16_t)((v.z + bv) * sc);
          dst[3 * HDIM] = (bf16_t)((v.w + bv) * sc);
        }
      }
    }
  } else {
#pragma unroll
    for (int mt = 0; mt < 4; mt++) {
#pragma unroll
      for (int nt = 0; nt < 4; nt++) {
        int m = m0 + wm * 64 + mt * 16 + lb * 4;
        int n = n0 + wn * 64 + nt * 16 + la;
        float bv = bias0[n];
        f32x4 v = acc[mt][nt];
        float* dst = Out + (size_t)m * D_MODEL + n;
        dst[0]           = v.x + bv;
        dst[D_MODEL]     = v.y + bv;
        dst[2 * D_MODEL] = v.z + bv;
        dst[3 * D_MODEL] = v.w + bv;
      }
    }
  }
}

// ---------------------------------------------------------------- causal flash attention
// Round-3 structure (q-tile 128, 4 warps/256thr, 2 blocks/CU for cross-block TLP) with
// K AND V double-buffered and the MID barrier DELETED. LDS exactly 80KB = 160/2:
// lK 2x16 + lV 2x16 + lP 16 (stride 64, col-XOR swizzled by (la&7)<<3).
// Per step exactly ONE __syncthreads: its per-wave vmcnt(0) drains K(kt)+V(kt) staged a
// FULL step earlier (= cheap); after the barrier buf^1 is provably dead for all warps
// (everyone finished step kt-1's reads) -> stage K/V(kt+1) there. P LDS round-trip is
// warp-local (warp w owns rows w*32..+31): compiler lgkm waits order write->read.
// (8-warp/qtile-256 variant refuted r5: 100KB LDS -> 1 blk/CU loses cross-block overlap,
// total +15us. Same-step V staging refuted r3 analysis: MID waits ~200-400cy/step.)
// Uniform grid: 512 blocks x 17 k-steps. idx<8: qt=8+idx partial [0,17);
// idx>=8: qtA=idx-8 full [0,2qtA+2) direct, then qt'=15-qtA partial [17, 32-2qtA).
// T13 defer-max: skip alpha-rescale when __all(tm - m <= 8).
__global__ __launch_bounds__(256, 2) void flash_attn(
    const bf16_t* __restrict__ Q, const bf16_t* __restrict__ Kg,
    const bf16_t* __restrict__ Vt, bf16_t* __restrict__ O,
    bf16_t* __restrict__ PO, float* __restrict__ ML) {
  __shared__ __align__(16) bf16_t lK[2][KT * 128];   // [j][d] chunks, swizzled; 2x16KB
  __shared__ __align__(16) bf16_t lV[2][128 * KT];   // [d][j] chunks, swizzled; 2x16KB
  __shared__ __align__(16) bf16_t lP[128 * 64];      // P^T [q][j^((q&7)<<3)]; 16KB
  const int g = blockIdx.x;
  const int bh = g & 31, idx = g >> 5;
  const int t = threadIdx.x;
  const int w = t >> 6, lane = t & 63;
  const int la = lane & 15, lb = lane >> 4;
  const int qloc = w * 32 + la;

  const bf16_t* Qb = Q + (size_t)bh * SEQ * HDIM;
  const bf16_t* Kb = Kg + (size_t)bh * SEQ * HDIM;
  const bf16_t* Vb = Vt + (size_t)bh * HDIM * SEQ;
  const int b = bh >> 4, h = bh & 15;

  int nph, qts[2], k0s[2], k1s[2], slots[2];
  bool parts[2];
  if (idx < 8) {
    nph = 1; qts[0] = 8 + idx; k0s[0] = 0; k1s[0] = 17;
    parts[0] = true; slots[0] = (idx * 32 + bh) * 2;
  } else {
    int qtA = idx - 8;
    nph = 2;
    qts[0] = qtA; k0s[0] = 0; k1s[0] = 2 * qtA + 2; parts[0] = false; slots[0] = 0;
    qts[1] = 15 - qtA; k0s[1] = 17; k1s[1] = 32 - 2 * qtA;
    parts[1] = true; slots[1] = ((7 - qtA) * 32 + bh) * 2 + 1;
  }

  // staging lane roles (fixed per thread); XOR chunk swizzles are involutions.
  const int krow = t >> 4, kcc = t & 15;   // K: 4 iters cover 64 rows x 16 chunks
  const int kccx = kcc ^ krow;             // krow in [0,16): (row&15) invariant under +16i
  const int vrow = t >> 3, vjc = t & 7;    // V: 4 iters cover 128 rows x 8 chunks
  const int vccx = vjc ^ (vrow & 7);       // (row&7) invariant under +32i

  auto stageKV = [&](int buf, int j0) {
#pragma unroll
    for (int i = 0; i < 4; i++)
      load_lds16(Kb + (size_t)(j0 + krow + 16 * i) * HDIM + kccx * 8,
                 lK[buf] + (t + 256 * i) * 8);
#pragma unroll
    for (int i = 0; i < 4; i++)
      load_lds16(Vb + (size_t)(vrow + 32 * i) * SEQ + j0 + vccx * 8,
                 lV[buf] + (t + 256 * i) * 8);
  };

  for (int ph = 0; ph < nph; ph++) {
    const int qt = qts[ph], kt0 = k0s[ph], kt1 = k1s[ph];
    const int q0 = qt * 128;

    // Q fragments (B-operand): Q[q0+qloc+16mt][32ks+8lb+i], prescaled by QSCALE
    bf16x8_t qf[2][4];
#pragma unroll
    for (int mt = 0; mt < 2; mt++)
#pragma unroll
      for (int ks = 0; ks < 4; ks++)
        qf[mt][ks] = *(const bf16x8_t*)(Qb + (size_t)(q0 + qloc + mt * 16) * HDIM + ks * 32 + lb * 8);

    f32x4 oacc[2][8];
    float mr[2] = {MINIT, MINIT}, lr[2] = {0.f, 0.f};
    f32x4 zero = {0.f, 0.f, 0.f, 0.f};
#pragma unroll
    for (int mt = 0; mt < 2; mt++)
#pragma unroll
      for (int dt = 0; dt < 8; dt++) oacc[mt][dt] = zero;

    // phase prologue: barrier protects lK/lV still read by the previous phase's tail.
    __syncthreads();
    stageKV(kt0 & 1, kt0 * KT);

    for (int kt = kt0; kt < kt1; kt++) {
      const int j0 = kt * KT;
      const int cur = kt & 1;

      // The ONE barrier: per-wave vmcnt(0) drains K/V(kt) (issued a full step ago ->
      // cheap); after it buf cur is resident chip-wide and buf cur^1 is dead.
      __syncthreads();
      if (kt + 1 < kt1) stageKV(cur ^ 1, (kt + 1) * KT);

      // S^T = K Q^T : rows j (4 nt tiles of 16), cols q (2 mt tiles)
      f32x4 st[4][2];
#pragma unroll
      for (int nt = 0; nt < 4; nt++)
#pragma unroll
        for (int mt = 0; mt < 2; mt++) st[nt][mt] = zero;
#pragma unroll
      for (int ks = 0; ks < 4; ks++) {
#pragma unroll
        for (int nt = 0; nt < 4; nt++) {
          int j = nt * 16 + la;
          int ck = (ks * 4 + lb) ^ la;   // j&15 == la
          bf16x8_t kf = *(const bf16x8_t*)(lK[cur] + j * 128 + ck * 8);
#pragma unroll
          for (int mt = 0; mt < 2; mt++)
            st[nt][mt] = __builtin_amdgcn_mfma_f32_16x16x32_bf16(kf, qf[mt][ks], st[nt][mt], 0, 0, 0);
        }
      }

      const bool dm = (j0 + KT > q0);  // diagonal-straddling (block-uniform)
#pragma unroll
      for (int mt = 0; mt < 2; mt++) {
        int qg = q0 + qloc + mt * 16;
        if (dm) {
#pragma unroll
          for (int nt = 0; nt < 4; nt++)
#pragma unroll
            for (int r = 0; r < 4; r++)
              if (j0 + nt * 16 + lb * 4 + r > qg) st[nt][mt][r] = NEGI;
        }
        float tm = NEGI;
#pragma unroll
        for (int nt = 0; nt < 4; nt++)
#pragma unroll
          for (int r = 0; r < 4; r++) tm = fmaxf(tm, st[nt][mt][r]);
        tm = fmaxf(tm, __shfl_xor(tm, 16));
        tm = fmaxf(tm, __shfl_xor(tm, 32));
        // T13 defer-max: only rescale when some row's max grew by > THR.
        if (!__all(tm - mr[mt] <= DEFER_THR)) {
          float mnew = fmaxf(mr[mt], tm);
          float alpha = exp2f(mr[mt] - mnew);
          lr[mt] *= alpha;
#pragma unroll
          for (int dt = 0; dt < 8; dt++) oacc[mt][dt] *= alpha;
          mr[mt] = mnew;
        }
        float s = 0.f;
#pragma unroll
        for (int nt = 0; nt < 4; nt++) {
          f32x4 p;
#pragma unroll
          for (int r = 0; r < 4; r++) {
            p[r] = exp2f(st[nt][mt][r] - mr[mt]);
            s += p[r];
          }
          bf16x4_t pk;
          pk.x = (bf16_t)p[0]; pk.y = (bf16_t)p[1]; pk.z = (bf16_t)p[2]; pk.w = (bf16_t)p[3];
          // P[q][j], j = nt*16+lb*4+r, stored at col j ^ ((q&7)<<3); (q&7)==(la&7).
          *(bf16x4_t*)(lP + (qloc + mt * 16) * 64 +
                       (((nt * 4 + lb) ^ ((la & 7) << 1)) * 4)) = pk;
        }
        s += __shfl_xor(s, 16);
        s += __shfl_xor(s, 32);
        lr[mt] += s;
      }

      // O^T += V^T P^T  (j = 64 -> two ks slices). lP rows warp-local; lgkm waits
      // order same-warp write->read; no barrier.
      bf16x8_t pf[2][2];
#pragma unroll
      for (int mt = 0; mt < 2; mt++)
#pragma unroll
        for (int ksv = 0; ksv < 2; ksv++)
          pf[mt][ksv] = *(const bf16x8_t*)(lP + (qloc + mt * 16) * 64 +
                                           ((ksv * 32 + lb * 8) ^ ((la & 7) << 3)));
#pragma unroll
      for (int dt = 0; dt < 8; dt++) {
        int d = dt * 16 + la;
#pragma unroll
        for (int ksv = 0; ksv < 2; ksv++) {
          int jc = (ksv * 4 + lb) ^ (d & 7);
          bf16x8_t vf = *(const bf16x8_t*)(lV[cur] + d * 64 + jc * 8);
#pragma unroll
          for (int mt = 0; mt < 2; mt++)
            oacc[mt][dt] = __builtin_amdgcn_mfma_f32_16x16x32_bf16(vf, pf[mt][ksv], oacc[mt][dt], 0, 0, 0);
        }
      }
    }

    if (!parts[ph]) {
#pragma unroll
      for (int mt = 0; mt < 2; mt++) {
        float inv = 1.0f / lr[mt];
        int q = q0 + qloc + mt * 16;
        bf16_t* dst = O + ((size_t)b * SEQ + q) * D_MODEL + h * HDIM + lb * 4;
#pragma unroll
        for (int dt = 0; dt < 8; dt++) {
          f32x4 v = oacc[mt][dt];
          bf16x4_t pk;
          pk.x = (bf16_t)(v[0] * inv); pk.y = (bf16_t)(v[1] * inv);
          pk.z = (bf16_t)(v[2] * inv); pk.w = (bf16_t)(v[3] * inv);
          *(bf16x4_t*)(dst + dt * 16) = pk;
        }
      }
    } else {
      const int slot = slots[ph];
      bf16_t* pob = PO + (size_t)slot * 128 * 128;
#pragma unroll
      for (int mt = 0; mt < 2; mt++) {
        int q = qloc + mt * 16;
        bf16_t* dst = pob + (size_t)q * 128 + lb * 4;
#pragma unroll
        for (int dt = 0; dt < 8; dt++) {
          f32x4 v = oacc[mt][dt];
          bf16x4_t pk;
          pk.x = (bf16_t)v[0]; pk.y = (bf16_t)v[1];
          pk.z = (bf16_t)v[2]; pk.w = (bf16_t)v[3];
          *(bf16x4_t*)(dst + dt * 16) = pk;
        }
        if (lb == 0) {
          float2 ml = make_float2(mr[mt], lr[mt]);
          *(float2*)(ML + ((size_t)slot * 128 + q) * 2) = ml;
        }
      }
    }
  }
}

// ---------------------------------------------------------------- merge split-j partials
__global__ void merge_kernel(const bf16_t* __restrict__ PO, const float* __restrict__ ML,
                             bf16_t* __restrict__ O) {
  const int qti = blockIdx.x >> 5, bh = blockIdx.x & 31;
  const int qt = 8 + qti;
  const int t = threadIdx.x;
  const int q = t >> 1, dh = (t & 1) * 64;
  const size_t s1 = ((size_t)(qti * 32 + bh)) * 2;
  const float* ml1 = ML + (s1 * 128 + q) * 2;
  const float* ml2 = ML + ((s1 + 1) * 128 + q) * 2;
  float m1 = ml1[0], l1 = ml1[1], m2 = ml2[0], l2 = ml2[1];
  float m = fmaxf(m1, m2);
  float w1 = exp2f(m1 - m), w2 = exp2f(m2 - m);
  float inv = 1.0f / (w1 * l1 + w2 * l2);
  w1 *= inv; w2 *= inv;
  const bf16_t* p1 = PO + (s1 * 128 + q) * 128 + dh;
  const bf16_t* p2 = PO + ((s1 + 1) * 128 + q) * 128 + dh;
  const int b = bh >> 4, h = bh & 15;
  bf16_t* dst = O + ((size_t)b * SEQ + qt * 128 + q) * D_MODEL + h * HDIM + dh;
#pragma unroll
  for (int i = 0; i < 8; i++) {
    bf16x8_t a = ((const bf16x8_t*)p1)[i];
    bf16x8_t c = ((const bf16x8_t*)p2)[i];
    bf16x8_t o;
#pragma unroll
    for (int e = 0; e < 8; e++)
      o[e] = (bf16_t)(w1 * (float)a[e] + w2 * (float)c[e]);
    ((bf16x8_t*)dst)[i] = o;
  }
}

// ---------------------------------------------------------------- launch
extern "C" void kernel_launch(void* const* d_in, const int* in_sizes, int n_in,
                              void* d_out, int out_size, void* d_ws, size_t ws_size,
                              hipStream_t stream) {
  (void)in_sizes; (void)n_in; (void)out_size; (void)ws_size;
  const float* x  = (const float*)d_in[0];
  const float* Wq = (const float*)d_in[2];
  const float* bq = (const float*)d_in[3];
  const float* Wk = (const float*)d_in[4];
  const float* bk = (const float*)d_in[5];
  const float* Wv = (const float*)d_in[6];
  const float* bv = (const float*)d_in[7];
  const float* Wo = (const float*)d_in[8];
  const float* bo = (const float*)d_in[9];
  float* out = (float*)d_out;

  const size_t NBF = (size_t)MTOT * D_MODEL * sizeof(bf16_t);    // 16.8 MB
  const size_t WBF = (size_t)D_MODEL * D_MODEL * sizeof(bf16_t); // 8.4 MB
  char* p = (char*)d_ws;
  bf16_t* xb   = (bf16_t*)p; p += NBF;       // reused as attention output O
  bf16_t* Wcat = (bf16_t*)p; p += 4 * WBF;   // [Wq|Wk|Wv|Wo] bf16
  bf16_t* Qb   = (bf16_t*)p; p += NBF;
  bf16_t* Kb   = (bf16_t*)p; p += NBF;
  bf16_t* Vtb  = (bf16_t*)p; p += NBF;
  bf16_t* Wob  = Wcat + (size_t)3 * D_MODEL * D_MODEL;
  bf16_t* Ob   = xb;
  // Partial buffers overlay dead Wq|Wk|Wv bf16 slots (dead after QKV GEMM):
  bf16_t* PO = Wcat;                                     // 512 slots * 16384 bf16 = 16.8 MB
  float*  ML = (float*)(Wcat + (size_t)512 * 128 * 128); // 0.5 MB

  const int WN4 = D_MODEL * D_MODEL / 4;
  const int XN4 = MTOT * D_MODEL / 4;
  cast_kernel<<<XN4 / 256, 256, 0, stream>>>(x, xb, XN4);
  cast4_kernel<<<dim3(WN4 / 256, 4), 256, 0, stream>>>(Wq, Wk, Wv, Wo, Wcat, WN4);

  gemm_fused<<<dim3(MTOT / 128, 6144 / 128), 256, 0, stream>>>(
      xb, Wcat, 0, bq, bk, bv, Qb, Kb, Vtb, nullptr);

  flash_attn<<<dim3(512), 256, 0, stream>>>(Qb, Kb, Vtb, Ob, PO, ML);
  merge_kernel<<<dim3(256), 256, 0, stream>>>(PO, ML, Ob);

  gemm_fused<<<dim3(MTOT / 128, D_MODEL / 128), 256, 0, stream>>>(
      Ob, Wob, 1, bo, nullptr, nullptr, nullptr, nullptr, nullptr, out);
}

// Round 7
// 372.198 us; speedup vs baseline: 1.0493x; 1.0298x over previous
//
#include <hip/hip_runtime.h>
#include <hip/hip_bf16.h>
#include <stdint.h>
#include <stddef.h>

typedef __bf16 bf16_t;
typedef __bf16 bf16x4_t __attribute__((ext_vector_type(4)));
typedef __bf16 bf16x8_t __attribute__((ext_vector_type(8)));
typedef float f32x4 __attribute__((ext_vector_type(4)));

#define D_MODEL 2048
#define NHEADS 16
#define HDIM 128
#define SEQ 2048
#define BATCH 2
#define MTOT (BATCH * SEQ) /* 4096 */
#define SCALE_F 0.08838834764831845f /* 1/sqrt(128) */
#define LOG2E 1.4426950408889634f
#define QSCALE (SCALE_F * LOG2E)
#define KT 64            /* flash K-tile */
#define NEGI -3.0e38f    /* mask value */
#define MINIT -1.0e30f   /* finite m sentinel: keeps exp2(masked - m) == 0 */
#define DEFER_THR 8.0f   /* T13 defer-max threshold (log2 units) */

#define AS1 __attribute__((address_space(1)))
#define AS3 __attribute__((address_space(3)))

__device__ __forceinline__ void load_lds16(const bf16_t* g, bf16_t* l) {
  __builtin_amdgcn_global_load_lds((AS1 void*)(g), (AS3 void*)(l), 16, 0, 0);
}

// ---------------------------------------------------------------- fused fp32->bf16 cast
// One launch for x (2^21 float4s) + Wq|Wk|Wv|Wo (4 x 2^20 float4s). All sizes pow2 ->
// branch-free segment decode. Grid 24576 x 256.
__global__ void cast_all_kernel(const float* __restrict__ x,
                                const float* __restrict__ w0, const float* __restrict__ w1,
                                const float* __restrict__ w2, const float* __restrict__ w3,
                                bf16_t* __restrict__ xb, bf16_t* __restrict__ wcat) {
  int i = blockIdx.x * blockDim.x + threadIdx.x;
  const int XN4 = MTOT * D_MODEL / 4;          // 2^21
  const int WN4 = D_MODEL * D_MODEL / 4;       // 2^20
  const float* src;
  bf16_t* dst;
  int idx;
  if (i < XN4) {
    src = x; dst = xb; idx = i;
  } else {
    int j = i - XN4;
    int y = j >> 20;          // which weight
    idx = j & (WN4 - 1);
    src = (y == 0) ? w0 : (y == 1) ? w1 : (y == 2) ? w2 : w3;
    dst = wcat + (size_t)y * D_MODEL * D_MODEL;
  }
  float4 v = ((const float4*)src)[idx];
  bf16x4_t o;
  o.x = (bf16_t)v.x; o.y = (bf16_t)v.y; o.z = (bf16_t)v.z; o.w = (bf16_t)v.w;
  ((bf16x4_t*)dst)[idx] = o;
}

// ---------------------------------------------------------------- GEMM  C = A @ B^T (+bias)
// BK=64, XOR chunk-swizzled LDS. mode 0: N=6144 (q|k|v) -> Q (prescaled by QSCALE), K,
// V transposed. mode 1: N=2048 -> fp32 out + bias.
// (Proven: ~122 us / 855 TF on the QKV shape = 95% of the m97-structure ceiling. 256^2
// 8-phase refuted for this shape: 384 tiles @ 1 blk/CU = 1.5 rounds packing; rounds 1-2.)
__global__ __launch_bounds__(256) void gemm_fused(
    const bf16_t* __restrict__ A, const bf16_t* __restrict__ Bm, int mode,
    const float* __restrict__ bias0, const float* __restrict__ bias1,
    const float* __restrict__ bias2,
    bf16_t* __restrict__ Qo, bf16_t* __restrict__ Ko, bf16_t* __restrict__ Vto,
    float* __restrict__ Out) {
  const int K = 2048;
  __shared__ __align__(16) bf16_t lA[128 * 64];
  __shared__ __align__(16) bf16_t lB[128 * 64];
  const int m0 = blockIdx.x * 128;
  const int n0 = blockIdx.y * 128;
  const int t = threadIdx.x;
  const int w = t >> 6, lane = t & 63;
  const int wm = w & 1, wn = w >> 1;
  const int la = lane & 15, lb = lane >> 4;

  f32x4 acc[4][4];
  f32x4 zero = {0.f, 0.f, 0.f, 0.f};
#pragma unroll
  for (int i = 0; i < 4; i++)
#pragma unroll
    for (int j = 0; j < 4; j++) acc[i][j] = zero;

  const int row0 = t >> 3, cc = t & 7;
  const int ccs = cc ^ (row0 & 7);
  const bf16_t* gA = A + (size_t)(m0 + row0) * K + ccs * 8;
  const bf16_t* gB = Bm + (size_t)(n0 + row0) * K + ccs * 8;
  bf16_t* sA = lA + t * 8;
  bf16_t* sB = lB + t * 8;

  for (int k0 = 0; k0 < K; k0 += 64) {
    __syncthreads();
#pragma unroll
    for (int i = 0; i < 4; i++)
      load_lds16(gA + k0 + (size_t)(32 * i) * K, sA + 2048 * i);
#pragma unroll
    for (int i = 0; i < 4; i++)
      load_lds16(gB + k0 + (size_t)(32 * i) * K, sB + 2048 * i);
    __syncthreads();
#pragma unroll
    for (int ks = 0; ks < 2; ks++) {
      bf16x8_t af[4], bfr[4];
#pragma unroll
      for (int mt = 0; mt < 4; mt++) {
        int row = wm * 64 + mt * 16 + la;
        af[mt] = *(const bf16x8_t*)(lA + row * 64 + (((ks * 4 + lb) ^ (la & 7)) * 8));
      }
#pragma unroll
      for (int nt = 0; nt < 4; nt++) {
        int row = wn * 64 + nt * 16 + la;
        bfr[nt] = *(const bf16x8_t*)(lB + row * 64 + (((ks * 4 + lb) ^ (la & 7)) * 8));
      }
#pragma unroll
      for (int mt = 0; mt < 4; mt++)
#pragma unroll
        for (int nt = 0; nt < 4; nt++)
          acc[mt][nt] = __builtin_amdgcn_mfma_f32_16x16x32_bf16(af[mt], bfr[nt], acc[mt][nt], 0, 0, 0);
    }
  }

  if (mode == 0) {
#pragma unroll
    for (int mt = 0; mt < 4; mt++) {
#pragma unroll
      for (int nt = 0; nt < 4; nt++) {
        int m = m0 + wm * 64 + mt * 16 + lb * 4;
        int n = n0 + wn * 64 + nt * 16 + la;
        int b = m >> 11, s = m & 2047;
        int which = n >> 11, hd = n & 2047;
        int h = hd >> 7, d = hd & 127;
        float bv = (which == 0 ? bias0 : which == 1 ? bias1 : bias2)[hd];
        f32x4 v = acc[mt][nt];
        if (which == 2) {
          bf16_t* dst = Vto + ((size_t)(b * NHEADS + h) * HDIM + d) * SEQ + s;
          bf16x4_t pk;
          pk.x = (bf16_t)(v.x + bv); pk.y = (bf16_t)(v.y + bv);
          pk.z = (bf16_t)(v.z + bv); pk.w = (bf16_t)(v.w + bv);
          *(bf16x4_t*)dst = pk;
        } else {
          float sc = (which == 0) ? QSCALE : 1.0f;
          bf16_t* dst = (which == 0 ? Qo : Ko) + ((size_t)(b * NHEADS + h) * SEQ + s) * HDIM + d;
          dst[0]        = (bf16_t)((v.x + bv) * sc);
          dst[HDIM]     = (bf16_t)((v.y + bv) * sc);
          dst[2 * HDIM] = (bf16_t)((v.z + bv) * sc);
          dst[3 * HDIM] = (bf16_t)((v.w + bv) * sc);
        }
      }
    }
  } else {
#pragma unroll
    for (int mt = 0; mt < 4; mt++) {
#pragma unroll
      for (int nt = 0; nt < 4; nt++) {
        int m = m0 + wm * 64 + mt * 16 + lb * 4;
        int n = n0 + wn * 64 + nt * 16 + la;
        float bv = bias0[n];
        f32x4 v = acc[mt][nt];
        float* dst = Out + (size_t)m * D_MODEL + n;
        dst[0]           = v.x + bv;
        dst[D_MODEL]     = v.y + bv;
        dst[2 * D_MODEL] = v.z + bv;
        dst[3 * D_MODEL] = v.w + bv;
      }
    }
  }
}

// ---------------------------------------------------------------- causal flash attention
// ROUND-3 PROVEN STRUCTURE (375.2us total): KT=64, q-tile 128, 4 warps, 2 blocks/CU.
// lK double-buffered; lV SINGLE-buffered, staged at step top (V first read after softmax
// >900cy later -> HBM latency hidden); MID = counted vmcnt(4) (V landed; K(kt+1) stays
// in flight) + raw s_barrier. T13 defer-max. LDS 66KB.
// r5 refuted: 8-warp/qtile-256 (100KB -> 1 blk/CU, lost cross-block TLP, +15us).
// r6 refuted: V-dbuf + single barrier (80KB, +8us vs this structure).
// NEW vs r3: T5 s_setprio(1) around QK^T and PV MFMA clusters — 2 independent blocks/CU
// = phase-diverse waves, the regime where attn setprio measured +4-7% (m191).
// Uniform grid: 512 blocks x exactly 17 k-steps. idx<8: qt=8+idx partial [0,17);
// idx>=8: qtA=idx-8 full [0,2qtA+2), then qt'=15-qtA partial [17, 32-2qtA).
__global__ __launch_bounds__(256, 2) void flash_attn(
    const bf16_t* __restrict__ Q, const bf16_t* __restrict__ Kg,
    const bf16_t* __restrict__ Vt, bf16_t* __restrict__ O,
    bf16_t* __restrict__ PO, float* __restrict__ ML) {
  __shared__ __align__(16) bf16_t lK[2][KT * 128];   // [j][d] chunks, swizzled; 2x16KB
  __shared__ __align__(16) bf16_t lV[128 * KT];      // [d][j] chunks, swizzled; 16KB
  __shared__ __align__(16) bf16_t lP[128 * 72];      // P^T as [q][j], stride 72; 18KB
  const int g = blockIdx.x;
  const int bh = g & 31, idx = g >> 5;
  const int t = threadIdx.x;
  const int w = t >> 6, lane = t & 63;
  const int la = lane & 15, lb = lane >> 4;
  const int qloc = w * 32 + la;

  const bf16_t* Qb = Q + (size_t)bh * SEQ * HDIM;
  const bf16_t* Kb = Kg + (size_t)bh * SEQ * HDIM;
  const bf16_t* Vb = Vt + (size_t)bh * HDIM * SEQ;
  const int b = bh >> 4, h = bh & 15;

  int nph, qts[2], k0s[2], k1s[2], slots[2];
  bool parts[2];
  if (idx < 8) {
    nph = 1; qts[0] = 8 + idx; k0s[0] = 0; k1s[0] = 17;
    parts[0] = true; slots[0] = (idx * 32 + bh) * 2;
  } else {
    int qtA = idx - 8;
    nph = 2;
    qts[0] = qtA; k0s[0] = 0; k1s[0] = 2 * qtA + 2; parts[0] = false; slots[0] = 0;
    qts[1] = 15 - qtA; k0s[1] = 17; k1s[1] = 32 - 2 * qtA;
    parts[1] = true; slots[1] = ((7 - qtA) * 32 + bh) * 2 + 1;
  }

  // staging lane roles (fixed per thread); XOR chunk swizzles are involutions.
  const int krow = t >> 4, kcc = t & 15;        // K: 4 iters cover 64 rows x 16 chunks
  const int kccx = kcc ^ krow;                  // (row&15) invariant under +16i
  const int vrow = t >> 3, vjc = t & 7;         // V: 4 iters cover 128 rows x 8 chunks
  const int vccx = vjc ^ (vrow & 7);            // (row&7) invariant under +32i

  for (int ph = 0; ph < nph; ph++) {
    const int qt = qts[ph], kt0 = k0s[ph], kt1 = k1s[ph];
    const int q0 = qt * 128;

    // Q fragments (B-operand): Q[q0+qloc+16mt][32ks+8lb+i], prescaled by QSCALE
    bf16x8_t qf[2][4];
#pragma unroll
    for (int mt = 0; mt < 2; mt++)
#pragma unroll
      for (int ks = 0; ks < 4; ks++)
        qf[mt][ks] = *(const bf16x8_t*)(Qb + (size_t)(q0 + qloc + mt * 16) * HDIM + ks * 32 + lb * 8);

    f32x4 oacc[2][8];
    float mr[2] = {MINIT, MINIT}, lr[2] = {0.f, 0.f};
    f32x4 zero = {0.f, 0.f, 0.f, 0.f};
#pragma unroll
    for (int mt = 0; mt < 2; mt++)
#pragma unroll
      for (int dt = 0; dt < 8; dt++) oacc[mt][dt] = zero;

    // phase prologue: stage K(kt0). Safe vs other warps: if this warp got here, all
    // warps passed the previous phase's last MID barrier => done reading lK.
    {
      const int j0 = kt0 * KT;
#pragma unroll
      for (int i = 0; i < 4; i++)
        load_lds16(Kb + (size_t)(j0 + krow + 16 * i) * HDIM + kccx * 8,
                   lK[kt0 & 1] + (t + 256 * i) * 8);
    }

    for (int kt = kt0; kt < kt1; kt++) {
      const int j0 = kt * KT;
      const int cur = kt & 1;
      const bool pre = (kt + 1 < kt1);

      // TOP: full drain (K(kt) issued a full step ago -> free) + barrier/fence.
      __syncthreads();

      // stage V(kt) into lV (single buffer; all PV(kt-1) reads ordered before TOP).
      // Issue V first (older) so MID's vmcnt(4) waits V while K(kt+1) stays in flight.
#pragma unroll
      for (int i = 0; i < 4; i++)
        load_lds16(Vb + (size_t)(vrow + 32 * i) * SEQ + j0 + vccx * 8,
                   lV + (t + 256 * i) * 8);
      if (pre) {
        const int jn = (kt + 1) * KT;
#pragma unroll
        for (int i = 0; i < 4; i++)
          load_lds16(Kb + (size_t)(jn + krow + 16 * i) * HDIM + kccx * 8,
                     lK[cur ^ 1] + (t + 256 * i) * 8);
      }

      // S^T = K Q^T : rows j (4 nt tiles of 16), cols q (2 mt tiles)
      f32x4 st[4][2];
#pragma unroll
      for (int nt = 0; nt < 4; nt++)
#pragma unroll
        for (int mt = 0; mt < 2; mt++) st[nt][mt] = zero;
      __builtin_amdgcn_s_setprio(1);
#pragma unroll
      for (int ks = 0; ks < 4; ks++) {
#pragma unroll
        for (int nt = 0; nt < 4; nt++) {
          int j = nt * 16 + la;
          int ck = (ks * 4 + lb) ^ la;   // j&15 == la
          bf16x8_t kf = *(const bf16x8_t*)(lK[cur] + j * 128 + ck * 8);
#pragma unroll
          for (int mt = 0; mt < 2; mt++)
            st[nt][mt] = __builtin_amdgcn_mfma_f32_16x16x32_bf16(kf, qf[mt][ks], st[nt][mt], 0, 0, 0);
        }
      }
      __builtin_amdgcn_s_setprio(0);

      const bool dm = (j0 + KT > q0);  // diagonal-straddling (block-uniform)
#pragma unroll
      for (int mt = 0; mt < 2; mt++) {
        int qg = q0 + qloc + mt * 16;
        if (dm) {
#pragma unroll
          for (int nt = 0; nt < 4; nt++)
#pragma unroll
            for (int r = 0; r < 4; r++)
              if (j0 + nt * 16 + lb * 4 + r > qg) st[nt][mt][r] = NEGI;
        }
        float tm = NEGI;
#pragma unroll
        for (int nt = 0; nt < 4; nt++)
#pragma unroll
          for (int r = 0; r < 4; r++) tm = fmaxf(tm, st[nt][mt][r]);
        tm = fmaxf(tm, __shfl_xor(tm, 16));
        tm = fmaxf(tm, __shfl_xor(tm, 32));
        // T13 defer-max: only rescale when some row's max grew by > THR.
        if (!__all(tm - mr[mt] <= DEFER_THR)) {
          float mnew = fmaxf(mr[mt], tm);
          float alpha = exp2f(mr[mt] - mnew);
          lr[mt] *= alpha;
#pragma unroll
          for (int dt = 0; dt < 8; dt++) oacc[mt][dt] *= alpha;
          mr[mt] = mnew;
        }
        float s = 0.f;
#pragma unroll
        for (int nt = 0; nt < 4; nt++) {
          f32x4 p;
#pragma unroll
          for (int r = 0; r < 4; r++) {
            p[r] = exp2f(st[nt][mt][r] - mr[mt]);
            s += p[r];
          }
          bf16x4_t pk;
          pk.x = (bf16_t)p[0]; pk.y = (bf16_t)p[1]; pk.z = (bf16_t)p[2]; pk.w = (bf16_t)p[3];
          *(bf16x4_t*)(lP + (qloc + mt * 16) * 72 + nt * 16 + lb * 4) = pk;
        }
        s += __shfl_xor(s, 16);
        s += __shfl_xor(s, 32);
        lr[mt] += s;
      }

      // MID: V(kt) landed (counted: K(kt+1)'s 4 loads stay in flight) + barrier.
      if (pre) {
        asm volatile("s_waitcnt vmcnt(4)" ::: "memory");
      } else {
        asm volatile("s_waitcnt vmcnt(0)" ::: "memory");
      }
      __builtin_amdgcn_s_barrier();

      // O^T += V^T P^T  (j = 64 -> two ks slices)
      bf16x8_t pf[2][2];
#pragma unroll
      for (int mt = 0; mt < 2; mt++)
#pragma unroll
        for (int ksv = 0; ksv < 2; ksv++)
          pf[mt][ksv] = *(const bf16x8_t*)(lP + (w * 32 + mt * 16 + la) * 72 + ksv * 32 + lb * 8);
      __builtin_amdgcn_s_setprio(1);
#pragma unroll
      for (int dt = 0; dt < 8; dt++) {
        int d = dt * 16 + la;
#pragma unroll
        for (int ksv = 0; ksv < 2; ksv++) {
          int jc = (ksv * 4 + lb) ^ (d & 7);
          bf16x8_t vf = *(const bf16x8_t*)(lV + d * 64 + jc * 8);
#pragma unroll
          for (int mt = 0; mt < 2; mt++)
            oacc[mt][dt] = __builtin_amdgcn_mfma_f32_16x16x32_bf16(vf, pf[mt][ksv], oacc[mt][dt], 0, 0, 0);
        }
      }
      __builtin_amdgcn_s_setprio(0);
    }

    if (!parts[ph]) {
#pragma unroll
      for (int mt = 0; mt < 2; mt++) {
        float inv = 1.0f / lr[mt];
        int q = q0 + qloc + mt * 16;
        bf16_t* dst = O + ((size_t)b * SEQ + q) * D_MODEL + h * HDIM + lb * 4;
#pragma unroll
        for (int dt = 0; dt < 8; dt++) {
          f32x4 v = oacc[mt][dt];
          bf16x4_t pk;
          pk.x = (bf16_t)(v[0] * inv); pk.y = (bf16_t)(v[1] * inv);
          pk.z = (bf16_t)(v[2] * inv); pk.w = (bf16_t)(v[3] * inv);
          *(bf16x4_t*)(dst + dt * 16) = pk;
        }
      }
    } else {
      const int slot = slots[ph];
      bf16_t* pob = PO + (size_t)slot * 128 * 128;
#pragma unroll
      for (int mt = 0; mt < 2; mt++) {
        int q = qloc + mt * 16;
        bf16_t* dst = pob + (size_t)q * 128 + lb * 4;
#pragma unroll
        for (int dt = 0; dt < 8; dt++) {
          f32x4 v = oacc[mt][dt];
          bf16x4_t pk;
          pk.x = (bf16_t)v[0]; pk.y = (bf16_t)v[1];
          pk.z = (bf16_t)v[2]; pk.w = (bf16_t)v[3];
          *(bf16x4_t*)(dst + dt * 16) = pk;
        }
        if (lb == 0) {
          float2 ml = make_float2(mr[mt], lr[mt]);
          *(float2*)(ML + ((size_t)slot * 128 + q) * 2) = ml;
        }
      }
    }
  }
}

// ---------------------------------------------------------------- merge split-j partials
__global__ void merge_kernel(const bf16_t* __restrict__ PO, const float* __restrict__ ML,
                             bf16_t* __restrict__ O) {
  const int qti = blockIdx.x >> 5, bh = blockIdx.x & 31;
  const int qt = 8 + qti;
  const int t = threadIdx.x;
  const int q = t >> 1, dh = (t & 1) * 64;
  const size_t s1 = ((size_t)(qti * 32 + bh)) * 2;
  const float* ml1 = ML + (s1 * 128 + q) * 2;
  const float* ml2 = ML + ((s1 + 1) * 128 + q) * 2;
  float m1 = ml1[0], l1 = ml1[1], m2 = ml2[0], l2 = ml2[1];
  float m = fmaxf(m1, m2);
  float w1 = exp2f(m1 - m), w2 = exp2f(m2 - m);
  float inv = 1.0f / (w1 * l1 + w2 * l2);
  w1 *= inv; w2 *= inv;
  const bf16_t* p1 = PO + (s1 * 128 + q) * 128 + dh;
  const bf16_t* p2 = PO + ((s1 + 1) * 128 + q) * 128 + dh;
  const int b = bh >> 4, h = bh & 15;
  bf16_t* dst = O + ((size_t)b * SEQ + qt * 128 + q) * D_MODEL + h * HDIM + dh;
#pragma unroll
  for (int i = 0; i < 8; i++) {
    bf16x8_t a = ((const bf16x8_t*)p1)[i];
    bf16x8_t c = ((const bf16x8_t*)p2)[i];
    bf16x8_t o;
#pragma unroll
    for (int e = 0; e < 8; e++)
      o[e] = (bf16_t)(w1 * (float)a[e] + w2 * (float)c[e]);
    ((bf16x8_t*)dst)[i] = o;
  }
}

// ---------------------------------------------------------------- launch
extern "C" void kernel_launch(void* const* d_in, const int* in_sizes, int n_in,
                              void* d_out, int out_size, void* d_ws, size_t ws_size,
                              hipStream_t stream) {
  (void)in_sizes; (void)n_in; (void)out_size; (void)ws_size;
  const float* x  = (const float*)d_in[0];
  const float* Wq = (const float*)d_in[2];
  const float* bq = (const float*)d_in[3];
  const float* Wk = (const float*)d_in[4];
  const float* bk = (const float*)d_in[5];
  const float* Wv = (const float*)d_in[6];
  const float* bv = (const float*)d_in[7];
  const float* Wo = (const float*)d_in[8];
  const float* bo = (const float*)d_in[9];
  float* out = (float*)d_out;

  const size_t NBF = (size_t)MTOT * D_MODEL * sizeof(bf16_t);    // 16.8 MB
  const size_t WBF = (size_t)D_MODEL * D_MODEL * sizeof(bf16_t); // 8.4 MB
  char* p = (char*)d_ws;
  bf16_t* xb   = (bf16_t*)p; p += NBF;       // reused as attention output O
  bf16_t* Wcat = (bf16_t*)p; p += 4 * WBF;   // [Wq|Wk|Wv|Wo] bf16
  bf16_t* Qb   = (bf16_t*)p; p += NBF;
  bf16_t* Kb   = (bf16_t*)p; p += NBF;
  bf16_t* Vtb  = (bf16_t*)p; p += NBF;
  bf16_t* Wob  = Wcat + (size_t)3 * D_MODEL * D_MODEL;
  bf16_t* Ob   = xb;
  // Partial buffers overlay dead Wq|Wk|Wv bf16 slots (dead after QKV GEMM):
  bf16_t* PO = Wcat;                                     // 512 slots * 16384 bf16 = 16.8 MB
  float*  ML = (float*)(Wcat + (size_t)512 * 128 * 128); // 0.5 MB

  const int XN4 = MTOT * D_MODEL / 4;          // 2^21
  const int WN4 = D_MODEL * D_MODEL / 4;       // 2^20
  cast_all_kernel<<<(XN4 + 4 * WN4) / 256, 256, 0, stream>>>(x, Wq, Wk, Wv, Wo, xb, Wcat);

  gemm_fused<<<dim3(MTOT / 128, 6144 / 128), 256, 0, stream>>>(
      xb, Wcat, 0, bq, bk, bv, Qb, Kb, Vtb, nullptr);

  flash_attn<<<dim3(512), 256, 0, stream>>>(Qb, Kb, Vtb, Ob, PO, ML);
  merge_kernel<<<dim3(256), 256, 0, stream>>>(PO, ML, Ob);

  gemm_fused<<<dim3(MTOT / 128, D_MODEL / 128), 256, 0, stream>>>(
      Ob, Wob, 1, bo, nullptr, nullptr, nullptr, nullptr, nullptr, out);
}